// Round 14
// baseline (580.785 us; speedup 1.0000x reference)
//
#include <hip/hip_runtime.h>
#include <hip/hip_bf16.h>
#include <math.h>

// ---------------- problem constants ----------------
#define NSEQ 22528
#define HALFSEQ 11264

typedef __attribute__((ext_vector_type(8))) short short8;
typedef __attribute__((ext_vector_type(4))) float f32x4;
typedef __attribute__((ext_vector_type(4))) ushort ushort4v;

__device__ __forceinline__ ushort f2bf(float x) {
    __hip_bfloat16 h = __float2bfloat16(x);
    return *reinterpret_cast<ushort*>(&h);
}
__device__ __forceinline__ float bf2f(ushort u) {
    unsigned v = ((unsigned)u) << 16;
    return *reinterpret_cast<float*>(&v);
}
__device__ __forceinline__ unsigned pkbf(float lo, float hi) {
    unsigned r;
    asm("v_cvt_pk_bf16_f32 %0, %1, %2" : "=v"(r) : "v"(lo), "v"(hi));
    return r;
}
__device__ __forceinline__ float fsilu(float y) {
    float e = __expf(-y);
    return y * __builtin_amdgcn_rcpf(1.f + e);
}

// ---------------- merged setup: WkT, kb, bvc, F, sh3 ----------------
// grid 2186: [0,2048) WkT | [2048,2056) kb | [2056] bvc | [2057,2185) F | [2185] sh3
__global__ __launch_bounds__(256) void k_prep_misc(
    const float* __restrict__ Wk, float* __restrict__ WkT,
    const float* __restrict__ bq, float* __restrict__ kb,
    const float* __restrict__ bv, const float* __restrict__ fca_w,
    const float* __restrict__ fca_b, float* __restrict__ bvc,
    const float* __restrict__ Wv, float* __restrict__ F,
    const float* __restrict__ b3c, const float* __restrict__ g3,
    const float* __restrict__ be3, const float* __restrict__ m3,
    const float* __restrict__ v3, float* __restrict__ sh3)
{
    __shared__ float smem[16 * 256];
    const int bid = blockIdx.x;
    const int tid = threadIdx.x;

    if (bid < 2048) {
        int idx = bid * 256 + tid;
        int b = idx >> 16;
        int rem = idx & 65535;
        int c = rem >> 8;
        int r = rem & 255;
        WkT[idx] = Wk[(size_t)(b * 256 + r) * 256 + c];
    } else if (bid < 2056) {
        int h = bid - 2048;
        smem[tid] = bq[h * 256 + tid];
        __syncthreads();
        const float* wk = Wk + (size_t)(h * 256 + tid) * 256;
        float a = 0.f;
        for (int o = 0; o < 256; ++o) a += wk[o] * smem[o];
        kb[h * 256 + tid] = a;
    } else if (bid < 2057) {
        for (int i = tid; i < 2048; i += 256) smem[i] = bv[i];
        __syncthreads();
        float acc = fca_b[tid];
        for (int k = 0; k < 2048; ++k) acc += smem[k] * fca_w[(size_t)k * 256 + tid];
        bvc[tid] = acc;
    } else if (bid < 2185) {
        int lb = bid - 2057;
        int h = lb >> 4;
        int e0 = (lb & 15) * 16;
        for (int idx = tid; idx < 4096; idx += 256) {
            int r = idx >> 8;
            int c = idx & 255;
            smem[r * 256 + c] = Wv[(size_t)h * 65536 + (e0 + r) * 256 + c];
        }
        __syncthreads();
        float acc[16];
        #pragma unroll
        for (int r = 0; r < 16; ++r) acc[r] = 0.f;
        for (int o = 0; o < 256; ++o) {
            float w = fca_w[(size_t)(h * 256 + o) * 256 + tid];
            #pragma unroll
            for (int r = 0; r < 16; ++r) acc[r] += smem[r * 256 + o] * w;
        }
        #pragma unroll
        for (int r = 0; r < 16; ++r)
            F[(size_t)(h * 256 + e0 + r) * 256 + tid] = acc[r];
    } else {
        float A = g3[tid] * rsqrtf(v3[tid] + 1e-5f);
        sh3[tid] = (b3c[tid] - m3[tid]) * A + be3[tid];
    }
}

// ---------------- merged packs: w2f | w3f | kbf.  grid 96 ----------------
__global__ __launch_bounds__(256) void k_prep_packs(
    const float* __restrict__ w2, ushort* __restrict__ w2f,
    const float* __restrict__ g2, const float* __restrict__ v2,
    const float* __restrict__ w3, ushort* __restrict__ w3f,
    const float* __restrict__ g3, const float* __restrict__ v3,
    const float* __restrict__ kb, ushort* __restrict__ kbf)
{
    __shared__ float tile[13312];
    const int bid = blockIdx.x;
    const int tid = threadIdx.x;

    if (bid < 16) {
        const int mt = bid >> 1;
        const int ich = bid & 1;
        for (int idx = tid; idx < 13312; idx += 256) {
            int oc16 = idx / 832;
            int rem = idx - oc16 * 832;
            tile[idx] = w2[(size_t)(mt * 16 + oc16) * 1664 + ich * 832 + rem];
        }
        __syncthreads();
        for (int wi = tid; wi < 26 * 512; wi += 256) {
            int t = wi >> 9;
            int li = wi & 511;
            int lane = li >> 3;
            int j = li & 7;
            int oc16 = lane & 15;
            int il = ((lane >> 4) << 3) + j;
            int oc = mt * 16 + oc16;
            float A = g2[oc] * rsqrtf(v2[oc] + 1e-5f);
            w2f[(size_t)(((2 * t + ich) * 8 + mt) << 9) + li] = f2bf(tile[oc16 * 832 + il * 26 + t] * A);
        }
    } else if (bid < 80) {
        const int lb = bid - 16;
        const int mt = lb >> 2;
        const int icb = lb & 3;
        for (int idx = tid; idx < 12800; idx += 256) {
            int oc16 = idx / 800;
            int rem = idx - oc16 * 800;
            tile[idx] = w3[(size_t)(mt * 16 + oc16) * 3200 + icb * 800 + rem];
        }
        __syncthreads();
        for (int wi = tid; wi < 25 * 512; wi += 256) {
            int pos = wi >> 9;
            int li = wi & 511;
            int lane = li >> 3;
            int j = li & 7;
            int oc16 = lane & 15;
            int il = ((lane >> 4) << 3) + j;
            int oc = mt * 16 + oc16;
            float A = g3[oc] * rsqrtf(v3[oc] + 1e-5f);
            w3f[(size_t)(((pos * 4 + icb) * 16 + mt) << 9) + li] = f2bf(tile[oc16 * 800 + il * 25 + pos] * A);
        }
    } else {
        int idx = (bid - 80) * 256 + tid;   // 4096 total
        int j = idx & 7;
        int lane = (idx >> 3) & 63;
        int kt = idx >> 9;
        int h = lane & 15;
        int e = kt * 32 + ((lane >> 4) << 3) + j;
        kbf[idx] = (h < 8) ? f2bf(kb[h * 256 + e]) : (ushort)0;
    }
}

// ---------------- setup: M = Wq Wk^T, written DIRECTLY to Mfrag (bf16) ----------------
// grid 128 = h*16 + e-tile.  Index map verified against old k_prep_mfrag:
// kt=e>>5, mt=o>>4, lane=(o&15)+16*((e>>3)&3), j=e&7.
__global__ __launch_bounds__(256) void k_prep_attn_m(
    const float* __restrict__ Wq, const float* __restrict__ WkT,
    ushort* __restrict__ Mfrag)
{
    const int h = blockIdx.x >> 4;
    const int e0 = (blockIdx.x & 15) * 16;
    const int tid = threadIdx.x;
    __shared__ float sq[16][256];
    for (int idx = tid; idx < 4096; idx += 256) {
        int r = idx >> 8;
        int c = idx & 255;
        sq[r][c] = Wq[(size_t)(h * 256 + e0 + r) * 256 + c];
    }
    __syncthreads();
    float acc[16];
    #pragma unroll
    for (int r = 0; r < 16; ++r) acc[r] = 0.f;
    const float* wkt = WkT + (size_t)h * 65536 + tid;
    for (int o = 0; o < 256; ++o) {
        float wk = wkt[o * 256];
        #pragma unroll
        for (int r = 0; r < 16; ++r) acc[r] += sq[r][o] * wk;
    }
    const int o = tid;
    const int mt = o >> 4;
    const int ob = o & 15;
    #pragma unroll
    for (int r = 0; r < 16; ++r) {
        int e = e0 + r;
        int kt = e >> 5;
        int lane = ob + 16 * ((e >> 3) & 3);
        int j = e & 7;
        Mfrag[(size_t)h * 65536 + (size_t)(kt * 16 + mt) * 512 + lane * 8 + j] = f2bf(acc[r]);
    }
}

// ---------------- conv1 + conv2 MFMA, J=8 seqs/block, 512 threads ----------------
__global__ __launch_bounds__(512, 4) void k_conv(
    const float* __restrict__ av1, const float* __restrict__ av2,
    const float* __restrict__ w1,
    const float* __restrict__ b1c, const float* __restrict__ g1,
    const float* __restrict__ be1, const float* __restrict__ m1, const float* __restrict__ v1,
    const ushort* __restrict__ w2f,
    const float* __restrict__ b2c, const float* __restrict__ g2,
    const float* __restrict__ be2, const float* __restrict__ m2, const float* __restrict__ v2,
    ushort* __restrict__ a2f, int seqoff)
{
    __shared__ ushort s_a1[8 * 3208];
    __shared__ ushort s_w1f[2048];
    __shared__ ushort s_xb[8][80];
    __shared__ float s_sh1[64], s_sh2[128];

    const int tid = threadIdx.x;
    const int lane = tid & 63;
    const int w = tid >> 6;
    const int l15 = lane & 15;
    const int grp = lane >> 4;
    const int lseq0 = blockIdx.x * 8;
    const int gseq0 = seqoff + lseq0;

    for (int idx = tid; idx < 640; idx += 512) {
        int s = idx / 80;
        int i = idx - s * 80;
        int seq = gseq0 + s;
        const float* src;
        if (seq < HALFSEQ) { int b = seq / 22; int n = seq - b * 22; src = av1 + b * 600 + n * 25; }
        else { int q = seq - HALFSEQ; int b = q / 22; int n = q - b * 22; src = av2 + b * 600 + n * 25; }
        s_xb[s][i] = f2bf((i < 75) ? src[i] : 0.f);
    }
    for (int idx = tid; idx < 2048; idx += 512) {
        int j = idx & 7;
        int ln = (idx >> 3) & 63;
        int mt = idx >> 9;
        int oc = mt * 16 + (ln & 15);
        int k = ((ln >> 4) << 3) + j;
        float A = g1[oc] * rsqrtf(v1[oc] + 1e-5f);
        s_w1f[idx] = (k < 26) ? f2bf(w1[oc * 26 + k] * A) : (ushort)0;
    }
    if (tid < 64) {
        float A = g1[tid] * rsqrtf(v1[tid] + 1e-5f);
        s_sh1[tid] = (b1c[tid] - m1[tid]) * A + be1[tid];
    }
    if (tid >= 128 && tid < 256) {
        int o = tid - 128;
        float A = g2[o] * rsqrtf(v2[o] + 1e-5f);
        s_sh2[o] = (b2c[o] - m2[o]) * A + be2[o];
    }
    __syncthreads();

    // ---- conv1 MFMA ----
    {
        short8 a1f[4];
        #pragma unroll
        for (int mt = 0; mt < 4; ++mt)
            a1f[mt] = *(const short8*)(s_w1f + mt * 512 + lane * 8);

        for (int nt = w; nt < 25; nt += 8) {
            int n = nt * 16 + l15;
            int s = n / 50;
            int p = n - s * 50;
            short8 bf;
            #pragma unroll
            for (int j = 0; j < 8; ++j) {
                int t = grp * 8 + j;
                bf[j] = (t < 26) ? (short)s_xb[s][p + t] : (short)0;
            }
            #pragma unroll
            for (int mt = 0; mt < 4; ++mt) {
                f32x4 acc1 = (f32x4){0.f, 0.f, 0.f, 0.f};
                acc1 = __builtin_amdgcn_mfma_f32_16x16x32_bf16(a1f[mt], bf, acc1, 0, 0, 0);
                int oc0 = mt * 16 + grp * 4;
                int icb = oc0 >> 3;
                int boff = s * 6416 + icb * 800 + p * 16 + (oc0 & 7) * 2;
                float y0 = fsilu(acc1[0] + s_sh1[oc0 + 0]);
                float y1 = fsilu(acc1[1] + s_sh1[oc0 + 1]);
                float y2 = fsilu(acc1[2] + s_sh1[oc0 + 2]);
                float y3 = fsilu(acc1[3] + s_sh1[oc0 + 3]);
                uint2 u;
                u.x = pkbf(y0, y1);
                u.y = pkbf(y2, y3);
                *(uint2*)((char*)s_a1 + boff) = u;
            }
        }
    }
    __syncthreads();

    // ---- conv2 MFMA: C[oc 128][n 208 (200 valid)] over K=1664 ----
    {
        const int mset = w & 3;
        const int nset = w >> 2;
        const int NT = nset ? 6 : 7;

        int vaddr[7];
        #pragma unroll
        for (int ni = 0; ni < 7; ++ni) {
            int nt = nset * 7 + ni;
            int n = nt * 16 + l15;
            int s = n / 25; if (s > 7) s = 7;
            int p = n - s * 25; if (p > 24) p = 24;
            vaddr[ni] = s * 6416 + grp * 800 + p * 16;
        }

        f32x4 acc[2][7];
        #pragma unroll
        for (int mi = 0; mi < 2; ++mi)
            #pragma unroll
            for (int ni = 0; ni < 7; ++ni)
                acc[mi][ni] = (f32x4){0.f, 0.f, 0.f, 0.f};

        const ushort* wpt = w2f + (size_t)(mset * 2) * 512 + lane * 8;
        short8 afA0 = *(const short8*)(wpt);
        short8 afA1 = *(const short8*)(wpt + 512);
        short8 afB0 = *(const short8*)(wpt + 4096);
        short8 afB1 = *(const short8*)(wpt + 4096 + 512);

        for (int t = 0; t < 26; ++t) {
            #pragma unroll
            for (int ni = 0; ni < 7; ++ni) {
                if (ni >= NT) break;
                short8 bf = *(const short8*)((const char*)s_a1 + vaddr[ni]);
                acc[0][ni] = __builtin_amdgcn_mfma_f32_16x16x32_bf16(afA0, bf, acc[0][ni], 0, 0, 0);
                acc[1][ni] = __builtin_amdgcn_mfma_f32_16x16x32_bf16(afA1, bf, acc[1][ni], 0, 0, 0);
            }
            if (t < 25) {
                afA0 = *(const short8*)(wpt + 8192);
                afA1 = *(const short8*)(wpt + 8192 + 512);
            }
            #pragma unroll
            for (int ni = 0; ni < 7; ++ni) {
                if (ni >= NT) break;
                short8 bf = *(const short8*)((const char*)s_a1 + vaddr[ni] + 3200);
                acc[0][ni] = __builtin_amdgcn_mfma_f32_16x16x32_bf16(afB0, bf, acc[0][ni], 0, 0, 0);
                acc[1][ni] = __builtin_amdgcn_mfma_f32_16x16x32_bf16(afB1, bf, acc[1][ni], 0, 0, 0);
            }
            if (t < 25) {
                afB0 = *(const short8*)(wpt + 12288);
                afB1 = *(const short8*)(wpt + 12288 + 512);
                wpt += 8192;
            }
            #pragma unroll
            for (int ni = 0; ni < 7; ++ni) vaddr[ni] += 16;
        }

        // epilogue -> a2f (conv3 fragment order)
        #pragma unroll
        for (int mi = 0; mi < 2; ++mi) {
            const int ocb = mset * 32 + mi * 16 + grp * 4;
            const int grp_dst = (ocb >> 3) & 3;
            const int jb = ocb & 7;
            const int kthi = ocb >> 5;
            #pragma unroll
            for (int ni = 0; ni < 7; ++ni) {
                if (ni >= NT) break;
                int n = (nset * 7 + ni) * 16 + l15;
                if (n < 200) {
                    int s = n / 25;
                    int p = n - s * 25;
                    int seq = lseq0 + s;
                    int kt3 = p * 4 + kthi;
                    float y0 = fsilu(acc[mi][ni][0] + s_sh2[ocb + 0]);
                    float y1 = fsilu(acc[mi][ni][1] + s_sh2[ocb + 1]);
                    float y2 = fsilu(acc[mi][ni][2] + s_sh2[ocb + 2]);
                    float y3 = fsilu(acc[mi][ni][3] + s_sh2[ocb + 3]);
                    uint2 u;
                    u.x = pkbf(y0, y1);
                    u.y = pkbf(y2, y3);
                    *(uint2*)(a2f + (((size_t)(seq >> 4) * 100 + kt3) << 9)
                              + ((seq & 15) + 16 * grp_dst) * 8 + jb) = u;
                }
            }
        }
    }
}

// ---------------- conv3 MFMA: M=256, N=64, K=3200; 2-deep ping-pong prefetch ----------------
__global__ __launch_bounds__(256) void k_conv3(
    const ushort* __restrict__ a2f, const ushort* __restrict__ w3f,
    const float* __restrict__ sh3,
    float* __restrict__ feat, int seqoff)
{
    const int tid = threadIdx.x;
    const int lane = tid & 63;
    const int wv = tid >> 6;
    const int l15 = lane & 15;
    const int grp = lane >> 4;
    const int lseq0 = blockIdx.x * 64;

    f32x4 acc3[4][4];
    #pragma unroll
    for (int mi = 0; mi < 4; ++mi)
        #pragma unroll
        for (int nt = 0; nt < 4; ++nt)
            acc3[mi][nt] = (f32x4){0.f, 0.f, 0.f, 0.f};

    const ushort* bp = a2f + ((size_t)(lseq0 >> 4) * 100) * 512 + lane * 8;
    const ushort* ap = w3f + (size_t)(wv * 4) * 512 + lane * 8;

    short8 bfA[4], bfB[4], afA[4], afB[4];
    #pragma unroll
    for (int nt = 0; nt < 4; ++nt) bfA[nt] = *(const short8*)(bp + (size_t)(nt * 100) * 512);
    #pragma unroll
    for (int mi = 0; mi < 4; ++mi) afA[mi] = *(const short8*)(ap + mi * 512);

    for (int kt = 0; kt < 100; kt += 2) {
        // prefetch kt+1
        #pragma unroll
        for (int nt = 0; nt < 4; ++nt) bfB[nt] = *(const short8*)(bp + (size_t)(nt * 100 + kt + 1) * 512);
        #pragma unroll
        for (int mi = 0; mi < 4; ++mi) afB[mi] = *(const short8*)(ap + (size_t)(kt + 1) * 8192 + mi * 512);
        // compute kt
        #pragma unroll
        for (int mi = 0; mi < 4; ++mi)
            #pragma unroll
            for (int nt = 0; nt < 4; ++nt)
                acc3[mi][nt] = __builtin_amdgcn_mfma_f32_16x16x32_bf16(afA[mi], bfA[nt], acc3[mi][nt], 0, 0, 0);
        // prefetch kt+2
        if (kt < 98) {
            #pragma unroll
            for (int nt = 0; nt < 4; ++nt) bfA[nt] = *(const short8*)(bp + (size_t)(nt * 100 + kt + 2) * 512);
            #pragma unroll
            for (int mi = 0; mi < 4; ++mi) afA[mi] = *(const short8*)(ap + (size_t)(kt + 2) * 8192 + mi * 512);
        }
        // compute kt+1
        #pragma unroll
        for (int mi = 0; mi < 4; ++mi)
            #pragma unroll
            for (int nt = 0; nt < 4; ++nt)
                acc3[mi][nt] = __builtin_amdgcn_mfma_f32_16x16x32_bf16(afB[mi], bfB[nt], acc3[mi][nt], 0, 0, 0);
    }

    #pragma unroll
    for (int nt = 0; nt < 4; ++nt) {
        int gseq = seqoff + lseq0 + nt * 16 + l15;
        #pragma unroll
        for (int mi = 0; mi < 4; ++mi) {
            int oc = wv * 64 + mi * 16 + grp * 4;
            float4 o4;
            #pragma unroll
            for (int r = 0; r < 4; ++r)
                ((float*)&o4)[r] = fsilu(acc3[mi][nt][r] + sh3[oc + r]);
            *(float4*)(feat + (size_t)gseq * 256 + oc) = o4;
        }
    }
}

// ---------------- fused attention v3: 1 group/block, 256 threads, 4 blocks/CU ----------------
__global__ __launch_bounds__(256, 4) void k_attn_f(
    const float* __restrict__ feat, const ushort* __restrict__ Mfrag,
    const ushort* __restrict__ kbf, float* __restrict__ fbar_all)
{
    const int g = blockIdx.x;
    const int tid = threadIdx.x;
    const int lane = tid & 63;
    const int wv = tid >> 6;       // 0..3
    const int l15 = lane & 15;
    const int grp = lane >> 4;

    __shared__ __align__(16) ushort sfb[32 * 256];   // 16 KB bf16 swizzled
    __shared__ __align__(16) ushort sG[32 * 256];    // 16 KB
    __shared__ float sS[528];
    __shared__ float sbet[192];
    __shared__ float sab[24];

    char* const sfbb = (char*)sfb;
    char* const sGb = (char*)sG;

    for (int idx = tid; idx < 8192; idx += 256) {
        int s = idx >> 8;
        int e = idx & 255;
        float f = (s < 22) ? feat[(size_t)g * 5632 + s * 256 + e] : 0.f;
        int byte = s * 512 + ((e * 2) ^ ((s & 7) << 4));
        *(ushort*)(sfbb + byte) = f2bf(f);
    }
    __syncthreads();

    // beta via MFMA: waves 0..1 = row halves; D[t][h]
    if (wv < 2) {
        int rA = wv * 16 + l15;
        f32x4 acc = (f32x4){0.f, 0.f, 0.f, 0.f};
        for (int kt = 0; kt < 8; ++kt) {
            int e0b = (kt * 32 + grp * 8) * 2;
            short8 af = *(const short8*)(sfbb + rA * 512 + (e0b ^ ((rA & 7) << 4)));
            short8 bf = *(const short8*)(kbf + kt * 512 + lane * 8);
            acc = __builtin_amdgcn_mfma_f32_16x16x32_bf16(af, bf, acc, 0, 0, 0);
        }
        #pragma unroll
        for (int r = 0; r < 4; ++r) {
            int t = wv * 16 + grp * 4 + r;
            int h = l15;
            if (t < 22 && h < 8) sbet[h * 24 + t] = acc[r];
        }
    }
    __syncthreads();

    for (int h = 0; h < 8; ++h) {
        // G-step: wave wv owns f-tiles wv*4..wv*4+3; A = 2 row halves
        {
            f32x4 accg[2][4];
            #pragma unroll
            for (int mt = 0; mt < 2; ++mt)
                #pragma unroll
                for (int fi = 0; fi < 4; ++fi)
                    accg[mt][fi] = (f32x4){0.f, 0.f, 0.f, 0.f};

            const ushort* mfb = Mfrag + (size_t)h * 65536;
            for (int kt = 0; kt < 8; ++kt) {
                int e0b = (kt * 32 + grp * 8) * 2;
                int rA0 = l15, rA1 = 16 + l15;
                short8 af0 = *(const short8*)(sfbb + rA0 * 512 + (e0b ^ ((rA0 & 7) << 4)));
                short8 af1 = *(const short8*)(sfbb + rA1 * 512 + (e0b ^ ((rA1 & 7) << 4)));
                #pragma unroll
                for (int fi = 0; fi < 4; ++fi) {
                    int ft = wv * 4 + fi;
                    short8 bfm = *(const short8*)(mfb + (size_t)((kt * 16 + ft) << 9) + lane * 8);
                    accg[0][fi] = __builtin_amdgcn_mfma_f32_16x16x32_bf16(af0, bfm, accg[0][fi], 0, 0, 0);
                    accg[1][fi] = __builtin_amdgcn_mfma_f32_16x16x32_bf16(af1, bfm, accg[1][fi], 0, 0, 0);
                }
            }
            #pragma unroll
            for (int mt = 0; mt < 2; ++mt) {
                #pragma unroll
                for (int fi = 0; fi < 4; ++fi) {
                    int f = (wv * 4 + fi) * 16 + l15;
                    #pragma unroll
                    for (int r = 0; r < 4; ++r) {
                        int s = mt * 16 + grp * 4 + r;
                        if (s < 22) {
                            int byte = s * 512 + ((f * 2) ^ ((s & 7) << 4));
                            *(ushort*)(sGb + byte) = f2bf(accg[mt][fi][r]);
                        }
                    }
                }
            }
        }
        __syncthreads();

        // S-step: 4 tiles (2 mt x 2 nt), one per wave
        {
            int mt2 = wv >> 1;
            int nt2 = wv & 1;
            f32x4 sacc = (f32x4){0.f, 0.f, 0.f, 0.f};
            int sA = mt2 * 16 + l15;
            int tB = nt2 * 16 + l15;
            for (int kt = 0; kt < 8; ++kt) {
                int f0b = (kt * 32 + grp * 8) * 2;
                short8 ga = *(const short8*)(sGb + sA * 512 + (f0b ^ ((sA & 7) << 4)));
                short8 fb = *(const short8*)(sfbb + tB * 512 + (f0b ^ ((tB & 7) << 4)));
                sacc = __builtin_amdgcn_mfma_f32_16x16x32_bf16(ga, fb, sacc, 0, 0, 0);
            }
            #pragma unroll
            for (int r = 0; r < 4; ++r) {
                int s = mt2 * 16 + grp * 4 + r;
                int t = nt2 * 16 + l15;
                if (s < 22 && t < 22)
                    sS[s * 24 + t] = sacc[r] + sbet[h * 24 + t];
            }
        }
        __syncthreads();

        if (tid < 22) {
            float* row = sS + tid * 24;
            float mx = -1e30f;
            #pragma unroll
            for (int t = 0; t < 22; ++t) mx = fmaxf(mx, row[t]);
            float ex[22];
            float sum = 0.f;
            #pragma unroll
            for (int t = 0; t < 22; ++t) { float e2 = __expf(row[t] - mx); ex[t] = e2; sum += e2; }
            float inv = 1.f / sum;
            #pragma unroll
            for (int t = 0; t < 22; ++t) row[t] = ex[t] * inv;
        }
        __syncthreads();
        if (tid < 22) {
            int t = tid;
            float a = 0.f;
            #pragma unroll
            for (int s = 0; s < 22; ++s) a += sS[s * 24 + t];
            sab[t] = a * (1.f / 22.f);
        }
        __syncthreads();

        {
            int e2b = tid * 2;
            float a = 0.f;
            #pragma unroll
            for (int t = 0; t < 22; ++t) {
                ushort u = *(ushort*)(sfbb + t * 512 + (e2b ^ ((t & 7) << 4)));
                a += sab[t] * bf2f(u);
            }
            fbar_all[((size_t)g * 8 + h) * 256 + tid] = a;
        }
        __syncthreads();
    }
}

// ---------------- k_pool: 4 groups/block, grid 256 ----------------
__global__ __launch_bounds__(256) void k_pool(
    const float* __restrict__ fbar_all, const float* __restrict__ F,
    const float* __restrict__ bvc,
    const float* __restrict__ fc_w, const float* __restrict__ fc_b,
    float* __restrict__ out)
{
    const int g0 = blockIdx.x * 4;
    const int tid = threadIdx.x;
    __shared__ __align__(16) float sfb[4 * 2048];
    __shared__ __align__(16) float sp[4 * 256];
    for (int idx = tid; idx < 8192; idx += 256)
        sfb[idx] = fbar_all[(size_t)g0 * 8 * 256 + idx];
    __syncthreads();

    float p[4];
    float bb = bvc[tid];
    #pragma unroll
    for (int j = 0; j < 4; ++j) p[j] = bb;
    for (int k = 0; k < 2048; k += 4) {
        float f0 = F[(size_t)(k + 0) * 256 + tid];
        float f1 = F[(size_t)(k + 1) * 256 + tid];
        float f2 = F[(size_t)(k + 2) * 256 + tid];
        float f3 = F[(size_t)(k + 3) * 256 + tid];
        #pragma unroll
        for (int j = 0; j < 4; ++j) {
            float4 v = *(const float4*)(sfb + j * 2048 + k);
            p[j] += v.x * f0 + v.y * f1 + v.z * f2 + v.w * f3;
        }
    }
    #pragma unroll
    for (int j = 0; j < 4; ++j) sp[j * 256 + tid] = p[j];
    __syncthreads();

    float y[4];
    float fb = fc_b[tid];
    #pragma unroll
    for (int j = 0; j < 4; ++j) y[j] = fb;
    for (int e = 0; e < 256; ++e) {
        float w = fc_w[(size_t)e * 256 + tid];
        #pragma unroll
        for (int j = 0; j < 4; ++j) y[j] += sp[j * 256 + e] * w;
    }
    #pragma unroll
    for (int j = 0; j < 4; ++j)
        out[(size_t)(g0 + j) * 256 + tid] = y[j];
}

// ---------------- launch ----------------
extern "C" void kernel_launch(void* const* d_in, const int* in_sizes, int n_in,
                              void* d_out, int out_size, void* d_ws, size_t ws_size,
                              hipStream_t stream) {
    (void)in_sizes; (void)n_in; (void)out_size;

    const float* av1   = (const float*)d_in[0];
    const float* av2   = (const float*)d_in[1];
    const float* w1    = (const float*)d_in[2];
    const float* b1c   = (const float*)d_in[3];
    const float* g1    = (const float*)d_in[4];
    const float* be1   = (const float*)d_in[5];
    const float* m1    = (const float*)d_in[6];
    const float* v1    = (const float*)d_in[7];
    const float* w2    = (const float*)d_in[8];
    const float* b2c   = (const float*)d_in[9];
    const float* g2    = (const float*)d_in[10];
    const float* be2   = (const float*)d_in[11];
    const float* m2    = (const float*)d_in[12];
    const float* v2    = (const float*)d_in[13];
    const float* w3    = (const float*)d_in[14];
    const float* b3c   = (const float*)d_in[15];
    const float* g3    = (const float*)d_in[16];
    const float* be3   = (const float*)d_in[17];
    const float* m3    = (const float*)d_in[18];
    const float* v3    = (const float*)d_in[19];
    const float* Wq    = (const float*)d_in[20];
    const float* bq    = (const float*)d_in[21];
    const float* Wk    = (const float*)d_in[22];
    const float* bk    = (const float*)d_in[23];
    const float* Wv    = (const float*)d_in[24];
    const float* bv    = (const float*)d_in[25];
    const float* fca_w = (const float*)d_in[26];
    const float* fca_b = (const float*)d_in[27];
    const float* fc_w  = (const float*)d_in[28];
    const float* fc_b  = (const float*)d_in[29];
    (void)bk;

    float* ws = (float*)d_ws;
    float* feat = ws;                         //  5,767,168 f
    float* WkT  = feat + 5767168;             //    524,288 f
    float* kb   = WkT + 524288;               //      2,048 f
    float* bvc  = kb + 2048;                  //        256 f
    float* F    = bvc + 256;                  //    524,288 f
    float* fbar = F + 524288;                 //  2,097,152 f
    float* sh3  = fbar + 2097152;             //        256 f
    ushort* w2f = (ushort*)(sh3 + 256);       //    212,992 u16
    ushort* w3f = w2f + 212992;               //    819,200 u16
    ushort* mfr = w3f + 819200;               //    524,288 u16
    ushort* kbf = mfr + 524288;               //      4,096 u16
    ushort* region = kbf + 4096;              // a2f chunk

    size_t base_bytes = (size_t)((char*)region - (char*)d_ws);
    size_t budget = (ws_size > base_bytes + 4096) ? (ws_size - base_bytes - 4096) : 0;
    int ncA = 16;
    const int cand[5] = {1, 2, 4, 8, 16};
    for (int i = 0; i < 5; ++i) { if ((size_t)144179200 / cand[i] <= budget) { ncA = cand[i]; break; } }
    const int seqsA = NSEQ / ncA;

    // setup (3 launches)
    k_prep_misc<<<2186, 256, 0, stream>>>(Wk, WkT, bq, kb, bv, fca_w, fca_b, bvc, Wv, F,
                                          b3c, g3, be3, m3, v3, sh3);
    k_prep_packs<<<96, 256, 0, stream>>>(w2, w2f, g2, v2, w3, w3f, g3, v3, kb, kbf);
    k_prep_attn_m<<<128, 256, 0, stream>>>(Wq, WkT, mfr);

    // conv pipeline (a2f chunked through region)
    ushort* a2f = region;
    for (int c = 0; c < ncA; ++c) {
        int seqoff = c * seqsA;
        k_conv<<<seqsA / 8, 512, 0, stream>>>(av1, av2,
            w1, b1c, g1, be1, m1, v1,
            w2f, b2c, g2, be2, m2, v2,
            a2f, seqoff);
        k_conv3<<<seqsA / 64, 256, 0, stream>>>(a2f, w3f, sh3, feat, seqoff);
    }

    // fused attention + head
    k_attn_f<<<1024, 256, 0, stream>>>(feat, mfr, kbf, fbar);
    k_pool<<<256, 256, 0, stream>>>(fbar, F, bvc, fc_w, fc_b, (float*)d_out);
}

// Round 15
// 552.356 us; speedup vs baseline: 1.0515x; 1.0515x over previous
//
#include <hip/hip_runtime.h>
#include <hip/hip_bf16.h>
#include <math.h>

// ---------------- problem constants ----------------
#define NSEQ 22528
#define HALFSEQ 11264

typedef __attribute__((ext_vector_type(8))) short short8;
typedef __attribute__((ext_vector_type(4))) float f32x4;
typedef __attribute__((ext_vector_type(4))) ushort ushort4v;

__device__ __forceinline__ ushort f2bf(float x) {
    __hip_bfloat16 h = __float2bfloat16(x);
    return *reinterpret_cast<ushort*>(&h);
}
__device__ __forceinline__ float bf2f(ushort u) {
    unsigned v = ((unsigned)u) << 16;
    return *reinterpret_cast<float*>(&v);
}
// pack two f32 -> two bf16 (RNE) in one instr
__device__ __forceinline__ unsigned pkbf(float lo, float hi) {
    unsigned r;
    asm("v_cvt_pk_bf16_f32 %0, %1, %2" : "=v"(r) : "v"(lo), "v"(hi));
    return r;
}
// fast SiLU: y * rcp(1+exp(-y))
__device__ __forceinline__ float fsilu(float y) {
    float e = __expf(-y);
    return y * __builtin_amdgcn_rcpf(1.f + e);
}

// ---------------- merged setup: WkT, kb, bvc, F, sh3 ----------------
// grid 2186: [0,2048) WkT | [2048,2056) kb | [2056] bvc | [2057,2185) F | [2185] sh3
__global__ __launch_bounds__(256) void k_prep_misc(
    const float* __restrict__ Wk, float* __restrict__ WkT,
    const float* __restrict__ bq, float* __restrict__ kb,
    const float* __restrict__ bv, const float* __restrict__ fca_w,
    const float* __restrict__ fca_b, float* __restrict__ bvc,
    const float* __restrict__ Wv, float* __restrict__ F,
    const float* __restrict__ b3c, const float* __restrict__ g3,
    const float* __restrict__ be3, const float* __restrict__ m3,
    const float* __restrict__ v3, float* __restrict__ sh3)
{
    __shared__ float smem[16 * 256];
    const int bid = blockIdx.x;
    const int tid = threadIdx.x;

    if (bid < 2048) {
        int idx = bid * 256 + tid;
        int b = idx >> 16;
        int rem = idx & 65535;
        int c = rem >> 8;
        int r = rem & 255;
        WkT[idx] = Wk[(size_t)(b * 256 + r) * 256 + c];
    } else if (bid < 2056) {
        int h = bid - 2048;
        smem[tid] = bq[h * 256 + tid];
        __syncthreads();
        const float* wk = Wk + (size_t)(h * 256 + tid) * 256;
        float a = 0.f;
        for (int o = 0; o < 256; ++o) a += wk[o] * smem[o];
        kb[h * 256 + tid] = a;
    } else if (bid < 2057) {
        for (int i = tid; i < 2048; i += 256) smem[i] = bv[i];
        __syncthreads();
        float acc = fca_b[tid];
        for (int k = 0; k < 2048; ++k) acc += smem[k] * fca_w[(size_t)k * 256 + tid];
        bvc[tid] = acc;
    } else if (bid < 2185) {
        int lb = bid - 2057;
        int h = lb >> 4;
        int e0 = (lb & 15) * 16;
        for (int idx = tid; idx < 4096; idx += 256) {
            int r = idx >> 8;
            int c = idx & 255;
            smem[r * 256 + c] = Wv[(size_t)h * 65536 + (e0 + r) * 256 + c];
        }
        __syncthreads();
        float acc[16];
        #pragma unroll
        for (int r = 0; r < 16; ++r) acc[r] = 0.f;
        for (int o = 0; o < 256; ++o) {
            float w = fca_w[(size_t)(h * 256 + o) * 256 + tid];
            #pragma unroll
            for (int r = 0; r < 16; ++r) acc[r] += smem[r * 256 + o] * w;
        }
        #pragma unroll
        for (int r = 0; r < 16; ++r)
            F[(size_t)(h * 256 + e0 + r) * 256 + tid] = acc[r];
    } else {
        float A = g3[tid] * rsqrtf(v3[tid] + 1e-5f);
        sh3[tid] = (b3c[tid] - m3[tid]) * A + be3[tid];
    }
}

// ---------------- w2f fragment pack (BN2 scale folded) ----------------
__global__ __launch_bounds__(256) void k_prep_w2t(
    const float* __restrict__ w2, ushort* __restrict__ w2f,
    const float* __restrict__ g2, const float* __restrict__ v2)
{
    __shared__ float tile[13312];
    const int mt = blockIdx.x >> 1;
    const int ich = blockIdx.x & 1;
    const int tid = threadIdx.x;
    for (int idx = tid; idx < 13312; idx += 256) {
        int oc16 = idx / 832;
        int rem = idx - oc16 * 832;
        tile[idx] = w2[(size_t)(mt * 16 + oc16) * 1664 + ich * 832 + rem];
    }
    __syncthreads();
    for (int wi = tid; wi < 26 * 512; wi += 256) {
        int t = wi >> 9;
        int li = wi & 511;
        int lane = li >> 3;
        int j = li & 7;
        int oc16 = lane & 15;
        int il = ((lane >> 4) << 3) + j;
        int oc = mt * 16 + oc16;
        float A = g2[oc] * rsqrtf(v2[oc] + 1e-5f);
        w2f[(size_t)(((2 * t + ich) * 8 + mt) << 9) + li] = f2bf(tile[oc16 * 832 + il * 26 + t] * A);
    }
}

// ---------------- w3f fragment pack (BN3 scale folded) ----------------
__global__ __launch_bounds__(256) void k_prep_w3t(
    const float* __restrict__ w3, ushort* __restrict__ w3f,
    const float* __restrict__ g3, const float* __restrict__ v3)
{
    __shared__ float tile[12800];
    const int mt = blockIdx.x >> 2;
    const int icb = blockIdx.x & 3;
    const int tid = threadIdx.x;
    for (int idx = tid; idx < 12800; idx += 256) {
        int oc16 = idx / 800;
        int rem = idx - oc16 * 800;
        tile[idx] = w3[(size_t)(mt * 16 + oc16) * 3200 + icb * 800 + rem];
    }
    __syncthreads();
    for (int wi = tid; wi < 25 * 512; wi += 256) {
        int pos = wi >> 9;
        int li = wi & 511;
        int lane = li >> 3;
        int j = li & 7;
        int oc16 = lane & 15;
        int il = ((lane >> 4) << 3) + j;
        int oc = mt * 16 + oc16;
        float A = g3[oc] * rsqrtf(v3[oc] + 1e-5f);
        w3f[(size_t)(((pos * 4 + icb) * 16 + mt) << 9) + li] = f2bf(tile[oc16 * 800 + il * 25 + pos] * A);
    }
}

// ---------------- setup: M = Wq Wk^T ----------------
__global__ __launch_bounds__(256) void k_prep_attn_m(
    const float* __restrict__ Wq, const float* __restrict__ WkT,
    float* __restrict__ M)
{
    const int h = blockIdx.x >> 4;
    const int e0 = (blockIdx.x & 15) * 16;
    const int tid = threadIdx.x;
    __shared__ float sq[16][256];
    for (int idx = tid; idx < 4096; idx += 256) {
        int r = idx >> 8;
        int c = idx & 255;
        sq[r][c] = Wq[(size_t)(h * 256 + e0 + r) * 256 + c];
    }
    __syncthreads();
    float acc[16];
    #pragma unroll
    for (int r = 0; r < 16; ++r) acc[r] = 0.f;
    const float* wkt = WkT + (size_t)h * 65536 + tid;
    for (int o = 0; o < 256; ++o) {
        float wk = wkt[o * 256];
        #pragma unroll
        for (int r = 0; r < 16; ++r) acc[r] += sq[r][o] * wk;
    }
    #pragma unroll
    for (int r = 0; r < 16; ++r)
        M[(size_t)(h * 256 + e0 + r) * 256 + tid] = acc[r];
}

// ---------------- setup: Mfrag + kbf ----------------
__global__ void k_prep_mfrag(const float* __restrict__ M, ushort* __restrict__ Mfrag,
                             const float* __restrict__ kb, ushort* __restrict__ kbf) {
    int bid = blockIdx.x;
    int tid = threadIdx.x;
    if (bid < 2048) {
        int idx = bid * 256 + tid;
        int j = idx & 7;
        int lane = (idx >> 3) & 63;
        int mt = (idx >> 9) & 15;
        int kt = (idx >> 13) & 7;
        int h = idx >> 16;
        int e = kt * 32 + ((lane >> 4) << 3) + j;
        int o = mt * 16 + (lane & 15);
        Mfrag[idx] = f2bf(M[(size_t)(h * 256 + e) * 256 + o]);
    } else {
        int idx = (bid - 2048) * 256 + tid;
        int j = idx & 7;
        int lane = (idx >> 3) & 63;
        int kt = idx >> 9;
        int h = lane & 15;
        int e = kt * 32 + ((lane >> 4) << 3) + j;
        kbf[idx] = (h < 8) ? f2bf(kb[h * 256 + e]) : (ushort)0;
    }
}

// ---------------- conv1 + conv2 MFMA, J=8 seqs/block, 512 threads ----------------
// s_a1: per-seq stride 6416 B (4-bank skew).
__global__ __launch_bounds__(512, 4) void k_conv(
    const float* __restrict__ av1, const float* __restrict__ av2,
    const float* __restrict__ w1,
    const float* __restrict__ b1c, const float* __restrict__ g1,
    const float* __restrict__ be1, const float* __restrict__ m1, const float* __restrict__ v1,
    const ushort* __restrict__ w2f,
    const float* __restrict__ b2c, const float* __restrict__ g2,
    const float* __restrict__ be2, const float* __restrict__ m2, const float* __restrict__ v2,
    ushort* __restrict__ a2f, int seqoff)
{
    __shared__ ushort s_a1[8 * 3208];
    __shared__ ushort s_w1f[2048];
    __shared__ ushort s_xb[8][80];
    __shared__ float s_sh1[64], s_sh2[128];

    const int tid = threadIdx.x;
    const int lane = tid & 63;
    const int w = tid >> 6;
    const int l15 = lane & 15;
    const int grp = lane >> 4;
    const int lseq0 = blockIdx.x * 8;
    const int gseq0 = seqoff + lseq0;

    for (int idx = tid; idx < 640; idx += 512) {
        int s = idx / 80;
        int i = idx - s * 80;
        int seq = gseq0 + s;
        const float* src;
        if (seq < HALFSEQ) { int b = seq / 22; int n = seq - b * 22; src = av1 + b * 600 + n * 25; }
        else { int q = seq - HALFSEQ; int b = q / 22; int n = q - b * 22; src = av2 + b * 600 + n * 25; }
        s_xb[s][i] = f2bf((i < 75) ? src[i] : 0.f);
    }
    for (int idx = tid; idx < 2048; idx += 512) {
        int j = idx & 7;
        int ln = (idx >> 3) & 63;
        int mt = idx >> 9;
        int oc = mt * 16 + (ln & 15);
        int k = ((ln >> 4) << 3) + j;
        float A = g1[oc] * rsqrtf(v1[oc] + 1e-5f);
        s_w1f[idx] = (k < 26) ? f2bf(w1[oc * 26 + k] * A) : (ushort)0;
    }
    if (tid < 64) {
        float A = g1[tid] * rsqrtf(v1[tid] + 1e-5f);
        s_sh1[tid] = (b1c[tid] - m1[tid]) * A + be1[tid];
    }
    if (tid >= 128 && tid < 256) {
        int o = tid - 128;
        float A = g2[o] * rsqrtf(v2[o] + 1e-5f);
        s_sh2[o] = (b2c[o] - m2[o]) * A + be2[o];
    }
    __syncthreads();

    // ---- conv1 MFMA ----
    {
        short8 a1f[4];
        #pragma unroll
        for (int mt = 0; mt < 4; ++mt)
            a1f[mt] = *(const short8*)(s_w1f + mt * 512 + lane * 8);

        for (int nt = w; nt < 25; nt += 8) {
            int n = nt * 16 + l15;
            int s = n / 50;
            int p = n - s * 50;
            short8 bf;
            #pragma unroll
            for (int j = 0; j < 8; ++j) {
                int t = grp * 8 + j;
                bf[j] = (t < 26) ? (short)s_xb[s][p + t] : (short)0;
            }
            #pragma unroll
            for (int mt = 0; mt < 4; ++mt) {
                f32x4 acc1 = (f32x4){0.f, 0.f, 0.f, 0.f};
                acc1 = __builtin_amdgcn_mfma_f32_16x16x32_bf16(a1f[mt], bf, acc1, 0, 0, 0);
                int oc0 = mt * 16 + grp * 4;
                int icb = oc0 >> 3;
                int boff = s * 6416 + icb * 800 + p * 16 + (oc0 & 7) * 2;
                float y0 = fsilu(acc1[0] + s_sh1[oc0 + 0]);
                float y1 = fsilu(acc1[1] + s_sh1[oc0 + 1]);
                float y2 = fsilu(acc1[2] + s_sh1[oc0 + 2]);
                float y3 = fsilu(acc1[3] + s_sh1[oc0 + 3]);
                uint2 u;
                u.x = pkbf(y0, y1);
                u.y = pkbf(y2, y3);
                *(uint2*)((char*)s_a1 + boff) = u;
            }
        }
    }
    __syncthreads();

    // ---- conv2 MFMA: C[oc 128][n 208 (200 valid)] over K=1664 ----
    {
        const int mset = w & 3;
        const int nset = w >> 2;
        const int NT = nset ? 6 : 7;

        int vaddr[7];
        #pragma unroll
        for (int ni = 0; ni < 7; ++ni) {
            int nt = nset * 7 + ni;
            int n = nt * 16 + l15;
            int s = n / 25; if (s > 7) s = 7;
            int p = n - s * 25; if (p > 24) p = 24;
            vaddr[ni] = s * 6416 + grp * 800 + p * 16;
        }

        f32x4 acc[2][7];
        #pragma unroll
        for (int mi = 0; mi < 2; ++mi)
            #pragma unroll
            for (int ni = 0; ni < 7; ++ni)
                acc[mi][ni] = (f32x4){0.f, 0.f, 0.f, 0.f};

        const ushort* wpt = w2f + (size_t)(mset * 2) * 512 + lane * 8;
        short8 afA0 = *(const short8*)(wpt);
        short8 afA1 = *(const short8*)(wpt + 512);
        short8 afB0 = *(const short8*)(wpt + 4096);
        short8 afB1 = *(const short8*)(wpt + 4096 + 512);

        for (int t = 0; t < 26; ++t) {
            #pragma unroll
            for (int ni = 0; ni < 7; ++ni) {
                if (ni >= NT) break;
                short8 bf = *(const short8*)((const char*)s_a1 + vaddr[ni]);
                acc[0][ni] = __builtin_amdgcn_mfma_f32_16x16x32_bf16(afA0, bf, acc[0][ni], 0, 0, 0);
                acc[1][ni] = __builtin_amdgcn_mfma_f32_16x16x32_bf16(afA1, bf, acc[1][ni], 0, 0, 0);
            }
            if (t < 25) {
                afA0 = *(const short8*)(wpt + 8192);
                afA1 = *(const short8*)(wpt + 8192 + 512);
            }
            #pragma unroll
            for (int ni = 0; ni < 7; ++ni) {
                if (ni >= NT) break;
                short8 bf = *(const short8*)((const char*)s_a1 + vaddr[ni] + 3200);
                acc[0][ni] = __builtin_amdgcn_mfma_f32_16x16x32_bf16(afB0, bf, acc[0][ni], 0, 0, 0);
                acc[1][ni] = __builtin_amdgcn_mfma_f32_16x16x32_bf16(afB1, bf, acc[1][ni], 0, 0, 0);
            }
            if (t < 25) {
                afB0 = *(const short8*)(wpt + 12288);
                afB1 = *(const short8*)(wpt + 12288 + 512);
                wpt += 8192;
            }
            #pragma unroll
            for (int ni = 0; ni < 7; ++ni) vaddr[ni] += 16;
        }

        // epilogue -> a2f (conv3 fragment order)
        #pragma unroll
        for (int mi = 0; mi < 2; ++mi) {
            const int ocb = mset * 32 + mi * 16 + grp * 4;
            const int grp_dst = (ocb >> 3) & 3;
            const int jb = ocb & 7;
            const int kthi = ocb >> 5;
            #pragma unroll
            for (int ni = 0; ni < 7; ++ni) {
                if (ni >= NT) break;
                int n = (nset * 7 + ni) * 16 + l15;
                if (n < 200) {
                    int s = n / 25;
                    int p = n - s * 25;
                    int seq = lseq0 + s;
                    int kt3 = p * 4 + kthi;
                    float y0 = fsilu(acc[mi][ni][0] + s_sh2[ocb + 0]);
                    float y1 = fsilu(acc[mi][ni][1] + s_sh2[ocb + 1]);
                    float y2 = fsilu(acc[mi][ni][2] + s_sh2[ocb + 2]);
                    float y3 = fsilu(acc[mi][ni][3] + s_sh2[ocb + 3]);
                    uint2 u;
                    u.x = pkbf(y0, y1);
                    u.y = pkbf(y2, y3);
                    *(uint2*)(a2f + (((size_t)(seq >> 4) * 100 + kt3) << 9)
                              + ((seq & 15) + 16 * grp_dst) * 8 + jb) = u;
                }
            }
        }
    }
}

// ---------------- conv3 MFMA: M=256, N=64 seqs, K=3200 (256 threads, mi=4) ----------------
__global__ __launch_bounds__(256) void k_conv3(
    const ushort* __restrict__ a2f, const ushort* __restrict__ w3f,
    const float* __restrict__ sh3,
    float* __restrict__ feat, int seqoff)
{
    const int tid = threadIdx.x;
    const int lane = tid & 63;
    const int wv = tid >> 6;
    const int l15 = lane & 15;
    const int grp = lane >> 4;
    const int lseq0 = blockIdx.x * 64;

    f32x4 acc3[4][4];
    #pragma unroll
    for (int mi = 0; mi < 4; ++mi)
        #pragma unroll
        for (int nt = 0; nt < 4; ++nt)
            acc3[mi][nt] = (f32x4){0.f, 0.f, 0.f, 0.f};

    const ushort* bp = a2f + ((size_t)(lseq0 >> 4) * 100) * 512 + lane * 8;
    const ushort* ap = w3f + (size_t)(wv * 4) * 512 + lane * 8;

    for (int kt = 0; kt < 100; ++kt) {
        short8 bf[4];
        #pragma unroll
        for (int nt = 0; nt < 4; ++nt)
            bf[nt] = *(const short8*)(bp + (size_t)(nt * 100 + kt) * 512);
        #pragma unroll
        for (int mi = 0; mi < 4; ++mi) {
            short8 af = *(const short8*)(ap + (size_t)kt * 8192 + mi * 512);
            #pragma unroll
            for (int nt = 0; nt < 4; ++nt)
                acc3[mi][nt] = __builtin_amdgcn_mfma_f32_16x16x32_bf16(af, bf[nt], acc3[mi][nt], 0, 0, 0);
        }
    }

    #pragma unroll
    for (int nt = 0; nt < 4; ++nt) {
        int gseq = seqoff + lseq0 + nt * 16 + l15;
        #pragma unroll
        for (int mi = 0; mi < 4; ++mi) {
            int oc = wv * 64 + mi * 16 + grp * 4;
            float4 o4;
            #pragma unroll
            for (int r = 0; r < 4; ++r)
                ((float*)&o4)[r] = fsilu(acc3[mi][nt][r] + sh3[oc + r]);
            *(float4*)(feat + (size_t)gseq * 256 + oc) = o4;
        }
    }
}

// ---------------- fused attention v2: 2 groups/block, 512 threads (8 waves) ----------------
__global__ __launch_bounds__(512, 2) void k_attn_f(
    const float* __restrict__ feat, const ushort* __restrict__ Mfrag,
    const ushort* __restrict__ kbf, float* __restrict__ fbar_all)
{
    const int g0 = blockIdx.x * 2;
    const int tid = threadIdx.x;
    const int lane = tid & 63;
    const int wv = tid >> 6;
    const int l15 = lane & 15;
    const int grp = lane >> 4;

    __shared__ __align__(16) ushort sfb[2 * 32 * 256];
    __shared__ __align__(16) ushort sG[2 * 32 * 256];
    __shared__ float sS[2 * 528];
    __shared__ float sbet[2 * 192];
    __shared__ float sab[2 * 24];

    char* const sfbb = (char*)sfb;
    char* const sGb = (char*)sG;

    for (int idx = tid; idx < 16384; idx += 512) {
        int gg = idx >> 13;
        int s = (idx >> 8) & 31;
        int e = idx & 255;
        float f = (s < 22) ? feat[(size_t)(g0 + gg) * 5632 + s * 256 + e] : 0.f;
        int byte = gg * 16384 + s * 512 + ((e * 2) ^ ((s & 7) << 4));
        *(ushort*)(sfbb + byte) = f2bf(f);
    }
    __syncthreads();

    if (wv < 4) {
        int gg = wv >> 1;
        int rowb = (wv & 1) * 16;
        int rA = rowb + l15;
        f32x4 acc = (f32x4){0.f, 0.f, 0.f, 0.f};
        for (int kt = 0; kt < 8; ++kt) {
            int e0b = (kt * 32 + grp * 8) * 2;
            short8 af = *(const short8*)(sfbb + gg * 16384 + rA * 512 + (e0b ^ ((rA & 7) << 4)));
            short8 bf = *(const short8*)(kbf + kt * 512 + lane * 8);
            acc = __builtin_amdgcn_mfma_f32_16x16x32_bf16(af, bf, acc, 0, 0, 0);
        }
        #pragma unroll
        for (int r = 0; r < 4; ++r) {
            int t = rowb + grp * 4 + r;
            int h = l15;
            if (t < 22 && h < 8) sbet[gg * 192 + h * 24 + t] = acc[r];
        }
    }
    __syncthreads();

    for (int h = 0; h < 8; ++h) {
        {
            f32x4 accg[4][2];
            #pragma unroll
            for (int mt = 0; mt < 4; ++mt)
                #pragma unroll
                for (int fi = 0; fi < 2; ++fi)
                    accg[mt][fi] = (f32x4){0.f, 0.f, 0.f, 0.f};

            const ushort* mfb = Mfrag + (size_t)h * 65536;
            for (int kt = 0; kt < 8; ++kt) {
                int e0b = (kt * 32 + grp * 8) * 2;
                short8 af[4];
                #pragma unroll
                for (int mt = 0; mt < 4; ++mt) {
                    int gg = mt >> 1;
                    int rA = (mt & 1) * 16 + l15;
                    af[mt] = *(const short8*)(sfbb + gg * 16384 + rA * 512 + (e0b ^ ((rA & 7) << 4)));
                }
                #pragma unroll
                for (int fi = 0; fi < 2; ++fi) {
                    int ft = wv * 2 + fi;
                    short8 bfm = *(const short8*)(mfb + (size_t)((kt * 16 + ft) << 9) + lane * 8);
                    #pragma unroll
                    for (int mt = 0; mt < 4; ++mt)
                        accg[mt][fi] = __builtin_amdgcn_mfma_f32_16x16x32_bf16(af[mt], bfm, accg[mt][fi], 0, 0, 0);
                }
            }
            #pragma unroll
            for (int mt = 0; mt < 4; ++mt) {
                int gg = mt >> 1;
                #pragma unroll
                for (int fi = 0; fi < 2; ++fi) {
                    int f = (wv * 2 + fi) * 16 + l15;
                    #pragma unroll
                    for (int r = 0; r < 4; ++r) {
                        int s = (mt & 1) * 16 + grp * 4 + r;
                        if (s < 22) {
                            int byte = gg * 16384 + s * 512 + ((f * 2) ^ ((s & 7) << 4));
                            *(ushort*)(sGb + byte) = f2bf(accg[mt][fi][r]);
                        }
                    }
                }
            }
        }
        __syncthreads();

        {
            int gg = wv >> 2;
            int mt2 = (wv >> 1) & 1;
            int nt2 = wv & 1;
            f32x4 sacc = (f32x4){0.f, 0.f, 0.f, 0.f};
            int sA = mt2 * 16 + l15;
            int tB = nt2 * 16 + l15;
            for (int kt = 0; kt < 8; ++kt) {
                int f0b = (kt * 32 + grp * 8) * 2;
                short8 ga = *(const short8*)(sGb + gg * 16384 + sA * 512 + (f0b ^ ((sA & 7) << 4)));
                short8 fb = *(const short8*)(sfbb + gg * 16384 + tB * 512 + (f0b ^ ((tB & 7) << 4)));
                sacc = __builtin_amdgcn_mfma_f32_16x16x32_bf16(ga, fb, sacc, 0, 0, 0);
            }
            #pragma unroll
            for (int r = 0; r < 4; ++r) {
                int s = mt2 * 16 + grp * 4 + r;
                int t = nt2 * 16 + l15;
                if (s < 22 && t < 22)
                    sS[gg * 528 + s * 24 + t] = sacc[r] + sbet[gg * 192 + h * 24 + t];
            }
        }
        __syncthreads();

        if (tid < 44) {
            int gg = tid >= 22;
            int s = tid - gg * 22;
            float* row = sS + gg * 528 + s * 24;
            float mx = -1e30f;
            #pragma unroll
            for (int t = 0; t < 22; ++t) mx = fmaxf(mx, row[t]);
            float ex[22];
            float sum = 0.f;
            #pragma unroll
            for (int t = 0; t < 22; ++t) { float e2 = __expf(row[t] - mx); ex[t] = e2; sum += e2; }
            float inv = 1.f / sum;
            #pragma unroll
            for (int t = 0; t < 22; ++t) row[t] = ex[t] * inv;
        }
        __syncthreads();
        if (tid < 44) {
            int gg = tid >= 22;
            int t = tid - gg * 22;
            float a = 0.f;
            #pragma unroll
            for (int s = 0; s < 22; ++s) a += sS[gg * 528 + s * 24 + t];
            sab[gg * 24 + t] = a * (1.f / 22.f);
        }
        __syncthreads();

        {
            int gg = tid >> 8;
            int e = tid & 255;
            int e2b = e * 2;
            float a = 0.f;
            #pragma unroll
            for (int t = 0; t < 22; ++t) {
                ushort u = *(ushort*)(sfbb + gg * 16384 + t * 512 + (e2b ^ ((t & 7) << 4)));
                a += sab[gg * 24 + t] * bf2f(u);
            }
            fbar_all[((size_t)(g0 + gg) * 8 + h) * 256 + e] = a;
        }
        __syncthreads();
    }
}

// ---------------- k_pool: 4 groups/block, grid 256 ----------------
__global__ __launch_bounds__(256) void k_pool(
    const float* __restrict__ fbar_all, const float* __restrict__ F,
    const float* __restrict__ bvc,
    const float* __restrict__ fc_w, const float* __restrict__ fc_b,
    float* __restrict__ out)
{
    const int g0 = blockIdx.x * 4;
    const int tid = threadIdx.x;
    __shared__ __align__(16) float sfb[4 * 2048];
    __shared__ __align__(16) float sp[4 * 256];
    for (int idx = tid; idx < 8192; idx += 256)
        sfb[idx] = fbar_all[(size_t)g0 * 8 * 256 + idx];
    __syncthreads();

    float p[4];
    float bb = bvc[tid];
    #pragma unroll
    for (int j = 0; j < 4; ++j) p[j] = bb;
    for (int k = 0; k < 2048; k += 4) {
        float f0 = F[(size_t)(k + 0) * 256 + tid];
        float f1 = F[(size_t)(k + 1) * 256 + tid];
        float f2 = F[(size_t)(k + 2) * 256 + tid];
        float f3 = F[(size_t)(k + 3) * 256 + tid];
        #pragma unroll
        for (int j = 0; j < 4; ++j) {
            float4 v = *(const float4*)(sfb + j * 2048 + k);
            p[j] += v.x * f0 + v.y * f1 + v.z * f2 + v.w * f3;
        }
    }
    #pragma unroll
    for (int j = 0; j < 4; ++j) sp[j * 256 + tid] = p[j];
    __syncthreads();

    float y[4];
    float fb = fc_b[tid];
    #pragma unroll
    for (int j = 0; j < 4; ++j) y[j] = fb;
    for (int e = 0; e < 256; ++e) {
        float w = fc_w[(size_t)e * 256 + tid];
        #pragma unroll
        for (int j = 0; j < 4; ++j) y[j] += sp[j * 256 + e] * w;
    }
    #pragma unroll
    for (int j = 0; j < 4; ++j)
        out[(size_t)(g0 + j) * 256 + tid] = y[j];
}

// ---------------- launch ----------------
extern "C" void kernel_launch(void* const* d_in, const int* in_sizes, int n_in,
                              void* d_out, int out_size, void* d_ws, size_t ws_size,
                              hipStream_t stream) {
    (void)in_sizes; (void)n_in; (void)out_size;

    const float* av1   = (const float*)d_in[0];
    const float* av2   = (const float*)d_in[1];
    const float* w1    = (const float*)d_in[2];
    const float* b1c   = (const float*)d_in[3];
    const float* g1    = (const float*)d_in[4];
    const float* be1   = (const float*)d_in[5];
    const float* m1    = (const float*)d_in[6];
    const float* v1    = (const float*)d_in[7];
    const float* w2    = (const float*)d_in[8];
    const float* b2c   = (const float*)d_in[9];
    const float* g2    = (const float*)d_in[10];
    const float* be2   = (const float*)d_in[11];
    const float* m2    = (const float*)d_in[12];
    const float* v2    = (const float*)d_in[13];
    const float* w3    = (const float*)d_in[14];
    const float* b3c   = (const float*)d_in[15];
    const float* g3    = (const float*)d_in[16];
    const float* be3   = (const float*)d_in[17];
    const float* m3    = (const float*)d_in[18];
    const float* v3    = (const float*)d_in[19];
    const float* Wq    = (const float*)d_in[20];
    const float* bq    = (const float*)d_in[21];
    const float* Wk    = (const float*)d_in[22];
    const float* bk    = (const float*)d_in[23];
    const float* Wv    = (const float*)d_in[24];
    const float* bv    = (const float*)d_in[25];
    const float* fca_w = (const float*)d_in[26];
    const float* fca_b = (const float*)d_in[27];
    const float* fc_w  = (const float*)d_in[28];
    const float* fc_b  = (const float*)d_in[29];
    (void)bk;

    float* ws = (float*)d_ws;
    float* feat = ws;                         //  5,767,168 f
    float* Mm   = feat + 5767168;             //    524,288 f
    float* WkT  = Mm + 524288;                //    524,288 f
    float* kb   = WkT + 524288;               //      2,048 f
    float* bvc  = kb + 2048;                  //        256 f
    float* F    = bvc + 256;                  //    524,288 f
    float* fbar = F + 524288;                 //  2,097,152 f
    float* sh3  = fbar + 2097152;             //        256 f
    ushort* w2f = (ushort*)(sh3 + 256);       //    212,992 u16
    ushort* w3f = w2f + 212992;               //    819,200 u16
    ushort* mfr = w3f + 819200;               //    524,288 u16
    ushort* kbf = mfr + 524288;               //      4,096 u16
    ushort* region = kbf + 4096;              // a2f chunk

    size_t base_bytes = (size_t)((char*)region - (char*)d_ws);
    size_t budget = (ws_size > base_bytes + 4096) ? (ws_size - base_bytes - 4096) : 0;
    int ncA = 16;
    const int cand[5] = {1, 2, 4, 8, 16};
    for (int i = 0; i < 5; ++i) { if ((size_t)144179200 / cand[i] <= budget) { ncA = cand[i]; break; } }
    const int seqsA = NSEQ / ncA;

    // setup
    k_prep_misc<<<2186, 256, 0, stream>>>(Wk, WkT, bq, kb, bv, fca_w, fca_b, bvc, Wv, F,
                                          b3c, g3, be3, m3, v3, sh3);
    k_prep_w2t<<<16, 256, 0, stream>>>(w2, w2f, g2, v2);
    k_prep_w3t<<<64, 256, 0, stream>>>(w3, w3f, g3, v3);
    k_prep_attn_m<<<128, 256, 0, stream>>>(Wq, WkT, Mm);
    k_prep_mfrag<<<2064, 256, 0, stream>>>(Mm, mfr, kb, kbf);

    // conv pipeline (a2f chunked through region)
    ushort* a2f = region;
    for (int c = 0; c < ncA; ++c) {
        int seqoff = c * seqsA;
        k_conv<<<seqsA / 8, 512, 0, stream>>>(av1, av2,
            w1, b1c, g1, be1, m1, v1,
            w2f, b2c, g2, be2, m2, v2,
            a2f, seqoff);
        k_conv3<<<seqsA / 64, 256, 0, stream>>>(a2f, w3f, sh3, feat, seqoff);
    }

    // fused attention + head
    k_attn_f<<<512, 512, 0, stream>>>(feat, mfr, kbf, fbar);
    k_pool<<<256, 256, 0, stream>>>(fbar, F, bvc, fc_w, fc_b, (float*)d_out);
}